// Round 2
// baseline (191.762 us; speedup 1.0000x reference)
//
#include <hip/hip_runtime.h>

// PositionalEncoding: x[B,S,N,F] -> out[B,S,N,F+2], B=64,S=4096,N=25,F=3.
// out[...,0:3]=x; out[...,3]=||x_next-x||; out[...,4]=nan_to_num(acos(dot/(|x||x_next|)))
// x_next = step s+1 (self at s=S-1).
//
// Memory-bound: 78.6 MB read + 131.1 MB write -> ~33 us floor at 6.3 TB/s.
// R1 post-mortem: scalar dword loads/stores at 12/20 B lane stride ran at
// ~1.1 TB/s (line-split bound). R2: tile into LDS so ALL global traffic is
// dense float4.

constexpr int Nc = 25, Sc = 4096, Bc = 64;
constexpr int TILE_ROWS = 64;                 // rows (b,s) per block
constexpr int IN_TILE   = TILE_ROWS * 75;     // 4800 floats in per tile
constexpr int IN_LOAD4  = (IN_TILE + 75 + 3) / 4;  // 1219 float4 (incl. next-row overlap)
constexpr int OUT_TILE  = TILE_ROWS * 125;    // 8000 floats out per tile
constexpr int GROUPS_PER_TILE = TILE_ROWS * Nc;    // 1600
constexpr long TOTAL_FLOATS_IN = (long)Bc * Sc * 75;
constexpr int NUM_TILES = Bc * Sc / TILE_ROWS;     // 4096
constexpr int TILES_PER_BATCH = Sc / TILE_ROWS;    // 64 (pow2)

__global__ __launch_bounds__(256) void pe_kernel(const float* __restrict__ x,
                                                 float* __restrict__ out) {
    __shared__ float s_in[IN_LOAD4 * 4];      // 4876 floats = 19.5 KB
    __shared__ float s_out[OUT_TILE];         // 32 KB

    const int tile = blockIdx.x;
    const long base_in = (long)tile * IN_TILE;

    // ---- global -> LDS, dense float4 ----
    const float4* __restrict__ src4 = (const float4*)(x + base_in);
    float4* dst4 = (float4*)s_in;
    for (int i = threadIdx.x; i < IN_LOAD4; i += 256) {
        if (base_in + (long)i * 4 + 4 <= TOTAL_FLOATS_IN)  // only trims the very last tile
            dst4[i] = src4[i];
    }
    __syncthreads();

    // ---- compute 1600 groups from LDS ----
    const bool batch_final = ((tile & (TILES_PER_BATCH - 1)) == TILES_PER_BATCH - 1);
    for (int gl = threadIdx.x; gl < GROUPS_PER_TILE; gl += 256) {
        int lr = gl / Nc;                     // local row (magic-mul)
        int off = gl * 3;
        int noff = (batch_final && lr == TILE_ROWS - 1) ? off : off + 75;  // self-pair at s=S-1

        float x0 = s_in[off],  x1 = s_in[off + 1],  x2 = s_in[off + 2];
        float y0 = s_in[noff], y1 = s_in[noff + 1], y2 = s_in[noff + 2];

        float d0 = y0 - x0, d1 = y1 - x1, d2 = y2 - x2;
        float dist = sqrtf(d0 * d0 + d1 * d1 + d2 * d2);

        float dot = x0 * y0 + x1 * y1 + x2 * y2;
        float nx = sqrtf(x0 * x0 + x1 * x1 + x2 * x2);
        float ny = sqrtf(y0 * y0 + y1 * y1 + y2 * y2);
        float ang = acosf(dot / (nx * ny));   // NaN when |ratio|>1 from rounding
        if (isnan(ang)) ang = 0.0f;           // jnp.nan_to_num

        int oo = gl * 5;
        s_out[oo]     = x0;
        s_out[oo + 1] = x1;
        s_out[oo + 2] = x2;
        s_out[oo + 3] = dist;
        s_out[oo + 4] = ang;
    }
    __syncthreads();

    // ---- LDS -> global, dense float4 (8000 floats = exactly 2000 float4) ----
    const float4* so4 = (const float4*)s_out;
    float4* __restrict__ dstg = (float4*)(out + (long)tile * OUT_TILE);
    for (int i = threadIdx.x; i < OUT_TILE / 4; i += 256)
        dstg[i] = so4[i];
}

extern "C" void kernel_launch(void* const* d_in, const int* in_sizes, int n_in,
                              void* d_out, int out_size, void* d_ws, size_t ws_size,
                              hipStream_t stream) {
    const float* x = (const float*)d_in[0];
    float* out = (float*)d_out;
    pe_kernel<<<NUM_TILES, 256, 0, stream>>>(x, out);
}